// Round 1
// baseline (96.382 us; speedup 1.0000x reference)
//
#include <hip/hip_runtime.h>

// RBFNN L1-distance kernel for MI355X.
// K1: sim[b,o] = sum_k |x[b,k]-c[o,k]| via f16 packed sub + and(abs) + v_dot2_f32_f16.
//     32x64 output tile per 256-thread block (4 rows x 2 cols per thread), full K=512.
//     Grid = 256 blocks -> exactly 1 block (4 waves) per CU. Writes sim into d_out,
//     per-block max into d_ws (256 floats).
// K2: reduce the 256 block maxes in-register, out = beta * (max*1.001 - sim) in place.

typedef _Float16 h2 __attribute__((ext_vector_type(2)));
typedef float f4 __attribute__((ext_vector_type(4)));
typedef unsigned int u32x4 __attribute__((ext_vector_type(4)));
typedef unsigned int u32x2 __attribute__((ext_vector_type(2)));

#define DIM_B 1024
#define DIM_O 512
#define DIM_K 512
#define BM 32
#define BN 64
#define BK 64
#define KH (BK / 2) // half2 steps per chunk
#define W_DIST 1.001f

__device__ __forceinline__ h2 as_h2(unsigned int u) { h2 r; __builtin_memcpy(&r, &u, 4); return r; }
__device__ __forceinline__ unsigned int as_u(h2 h) { unsigned int r; __builtin_memcpy(&r, &h, 4); return r; }

__global__ __launch_bounds__(256) void k_sim(const float* __restrict__ X,
                                             const float* __restrict__ C,
                                             float* __restrict__ S,
                                             float* __restrict__ bmax)
{
    // k-major LDS: xs[k2][row], cs[k2][col]; XOR swizzle elem = idx ^ ((k2&7)<<2)
    // keeps b128/b64 reads conflict-free and cuts transpose-write conflicts to 4-way.
    __shared__ __align__(16) h2 xs[KH][BM]; // 4 KB
    __shared__ __align__(16) h2 cs[KH][BN]; // 8 KB
    const int tid = threadIdx.x;
    const int bx = blockIdx.x & 7;   // 8 col tiles
    const int by = blockIdx.x >> 3;  // 32 row tiles
    const int row0 = by * BM, col0 = bx * BN;
    const int tr = tid >> 5;  // 0..7  -> 4 rows each
    const int tc = tid & 31;  // 0..31 -> 2 cols each
    float acc[4][2] = {};
    const h2 one2 = {(_Float16)1.f, (_Float16)1.f};

    for (int k0 = 0; k0 < DIM_K; k0 += BK) {
        // stage X tile: 32 rows x 64 k = 512 float4 slots
#pragma unroll
        for (int p = 0; p < 2; ++p) {
            int s = tid + p * 256;
            int row = s >> 4, kv = s & 15;
            f4 v = *(const f4*)(X + (row0 + row) * DIM_K + k0 + kv * 4);
            int ka = 2 * kv, kb = ka + 1;
            h2 h0 = {(_Float16)v.x, (_Float16)v.y};
            h2 h1 = {(_Float16)v.z, (_Float16)v.w};
            xs[ka][row ^ ((ka & 7) << 2)] = h0;
            xs[kb][row ^ ((kb & 7) << 2)] = h1;
        }
        // stage C tile: 64 cols x 64 k = 1024 float4 slots
#pragma unroll
        for (int p = 0; p < 4; ++p) {
            int s = tid + p * 256;
            int row = s >> 4, kv = s & 15;
            f4 v = *(const f4*)(C + (col0 + row) * DIM_K + k0 + kv * 4);
            int ka = 2 * kv, kb = ka + 1;
            h2 h0 = {(_Float16)v.x, (_Float16)v.y};
            h2 h1 = {(_Float16)v.z, (_Float16)v.w};
            cs[ka][row ^ ((ka & 7) << 2)] = h0;
            cs[kb][row ^ ((kb & 7) << 2)] = h1;
        }
        __syncthreads();
#pragma unroll
        for (int k2 = 0; k2 < KH; ++k2) {
            const int sw = k2 & 7;
            u32x4 xu = *(const u32x4*)&xs[k2][4 * (tr ^ sw)];          // 4 rows, b128
            u32x2 cu = *(const u32x2*)&cs[k2][2 * (tc ^ (sw << 1))];   // 2 cols, b64
#pragma unroll
            for (int i = 0; i < 4; ++i) {
                h2 a = as_h2(xu[i]);
#pragma unroll
                for (int j = 0; j < 2; ++j) {
                    h2 d = a - as_h2(cu[j]);                       // v_pk_sub_f16
                    h2 ad = as_h2(as_u(d) & 0x7fff7fffu);          // abs both halves
                    acc[i][j] = __builtin_amdgcn_fdot2(ad, one2, acc[i][j], false);
                }
            }
        }
        __syncthreads();
    }

    // epilogue: write sim tile + per-block max
    const int r0 = row0 + tr * 4;
    const int c0 = col0 + tc * 2;
    float m = 0.f; // sims are >= 0
#pragma unroll
    for (int i = 0; i < 4; ++i) {
        float2 v = make_float2(acc[i][0], acc[i][1]);
        *(float2*)(S + (r0 + i) * DIM_O + c0) = v;
        m = fmaxf(m, fmaxf(v.x, v.y));
    }
#pragma unroll
    for (int off = 32; off > 0; off >>= 1)
        m = fmaxf(m, __shfl_xor(m, off, 64));
    __shared__ float wm[4];
    if ((tid & 63) == 0) wm[tid >> 6] = m;
    __syncthreads();
    if (tid == 0)
        bmax[blockIdx.x] = fmaxf(fmaxf(wm[0], wm[1]), fmaxf(wm[2], wm[3]));
}

__global__ __launch_bounds__(256) void k_out(float* __restrict__ S,
                                             const float* __restrict__ beta,
                                             const float* __restrict__ bmax)
{
    const int tid = threadIdx.x;
    const int lane = tid & 63;
    // reduce 256 block maxes per wave (redundant across waves, trivially cheap)
    float m = fmaxf(fmaxf(bmax[lane], bmax[lane + 64]),
                    fmaxf(bmax[lane + 128], bmax[lane + 192]));
#pragma unroll
    for (int off = 32; off > 0; off >>= 1)
        m = fmaxf(m, __shfl_xor(m, off, 64));
    const float shift = m * W_DIST;

    const int f = blockIdx.x * 256 + tid; // float4 index, 131072 total
    f4 s = ((const f4*)S)[f];
    f4 b = ((const f4*)beta)[f & 127]; // 128 float4 per row of 512 cols
    f4 r;
    r.x = b.x * (shift - s.x);
    r.y = b.y * (shift - s.y);
    r.z = b.z * (shift - s.z);
    r.w = b.w * (shift - s.w);
    ((f4*)S)[f] = r;
}

extern "C" void kernel_launch(void* const* d_in, const int* in_sizes, int n_in,
                              void* d_out, int out_size, void* d_ws, size_t ws_size,
                              hipStream_t stream) {
    const float* X = (const float*)d_in[0];
    const float* C = (const float*)d_in[1];
    const float* beta = (const float*)d_in[2];
    float* S = (float*)d_out;       // sim staged in d_out, transformed in place by k_out
    float* bmax = (float*)d_ws;     // 256 floats of scratch
    k_sim<<<256, 256, 0, stream>>>(X, C, S, bmax);
    k_out<<<512, 256, 0, stream>>>(S, beta, bmax);
}

// Round 3
// 79.577 us; speedup vs baseline: 1.2112x; 1.2112x over previous
//
#include <hip/hip_runtime.h>

// RBFNN L1-distance, round 2b: latency-oriented restructure (compile fix of r2).
// K1 (k_sim): 1024 blocks x 64 threads (1 wave). Tile 16x32, 8 outputs/thread
//   (r=4 rows, cols {tc, tc+16}). 4 independent single-wave blocks per CU ->
//   4 instruction streams, no shared barriers. Register prefetch of next
//   global tile overlaps compute. LDS row-major, stride 36 dwords:
//   fragment reads are ds_read_b128 (2-way banked = free), xs reads broadcast.
//   f16 math: v_pk_sub_f16 + v_and (abs) + v_dot2_f32_f16 = 1.5 inst/pair.
// K2 (k_out): reduce 1024 block maxes in-wave, out = beta*(max*1.001 - sim).

typedef _Float16 h2 __attribute__((ext_vector_type(2)));
typedef float f4 __attribute__((ext_vector_type(4)));
typedef unsigned int u32x4 __attribute__((ext_vector_type(4)));
typedef unsigned int u32x2 __attribute__((ext_vector_type(2)));

#define DIM_O 512
#define DIM_K 512
#define BM 16
#define BN 32
#define BK 64
#define LSTRIDE 36   // h2 (=dword) per LDS row: 32 data + 4 pad; 144B keeps 16B align,
                     // lane stride 36%32=4 -> 2-way bank aliasing (free per m136)
#define W_DIST 1.001f

__device__ __forceinline__ h2 as_h2(unsigned int u){ h2 r; __builtin_memcpy(&r,&u,4); return r; }
__device__ __forceinline__ unsigned int as_u(h2 h){ unsigned int r; __builtin_memcpy(&r,&h,4); return r; }
__device__ __forceinline__ unsigned int cvt2(float a, float b){
    // v_cvt_pkrtz_f16_f32 returns __fp16x2; move bits via memcpy (no implicit conv)
    auto h = __builtin_amdgcn_cvt_pkrtz(a, b);
    unsigned int r; __builtin_memcpy(&r, &h, 4); return r;
}

__global__ __launch_bounds__(64) void k_sim(const float* __restrict__ X,
                                            const float* __restrict__ C,
                                            float* __restrict__ S,
                                            float* __restrict__ bmax)
{
    __shared__ __align__(16) h2 xs[BM][LSTRIDE]; // 16*36*4B = 2304 B
    __shared__ __align__(16) h2 cs[BN][LSTRIDE]; // 32*36*4B = 4608 B
    const int tid = threadIdx.x;
    const int bx = blockIdx.x & 15;   // 16 col tiles (512/32)
    const int by = blockIdx.x >> 4;   // 64 row tiles (1024/16)
    const int row0 = by * BM, col0 = bx * BN;
    const int tr = tid >> 4;          // 0..3 -> rows tr*4..tr*4+3
    const int tc = tid & 15;          // 0..15 -> cols tc, tc+16
    float acc[4][2] = {};
    const h2 one2 = {(_Float16)1.f, (_Float16)1.f};

    // register prefetch buffers: X tile 16 rows x 16 f4 (4/thread),
    //                            C tile 32 rows x 16 f4 (8/thread)
    f4 xv[4], cv[8];
    const int srow = tid >> 4, skv = tid & 15; // staging slot base (p adds 4 rows)
#pragma unroll
    for (int p = 0; p < 4; ++p)
        xv[p] = *(const f4*)(X + (row0 + srow + 4 * p) * DIM_K + 4 * skv);
#pragma unroll
    for (int p = 0; p < 8; ++p)
        cv[p] = *(const f4*)(C + (col0 + srow + 4 * p) * DIM_K + 4 * skv);

    for (int t = 0; t < 8; ++t) {
        __syncthreads(); // single-wave: cheap; protects LDS reuse
#pragma unroll
        for (int p = 0; p < 4; ++p) {
            u32x2 w; w[0] = cvt2(xv[p].x, xv[p].y); w[1] = cvt2(xv[p].z, xv[p].w);
            *(u32x2*)&xs[srow + 4 * p][skv * 2] = w; // b64 write
        }
#pragma unroll
        for (int p = 0; p < 8; ++p) {
            u32x2 w; w[0] = cvt2(cv[p].x, cv[p].y); w[1] = cvt2(cv[p].z, cv[p].w);
            *(u32x2*)&cs[srow + 4 * p][skv * 2] = w;
        }
        __syncthreads();

        // issue next chunk's global loads; they fly during compute below
        const int kn = (t < 7) ? (t + 1) * BK : 0;
#pragma unroll
        for (int p = 0; p < 4; ++p)
            xv[p] = *(const f4*)(X + (row0 + srow + 4 * p) * DIM_K + kn + 4 * skv);
#pragma unroll
        for (int p = 0; p < 8; ++p)
            cv[p] = *(const f4*)(C + (col0 + srow + 4 * p) * DIM_K + kn + 4 * skv);

        // compute: 8 groups of 8 k (4 h2) each; all reads b128
#pragma unroll
        for (int g = 0; g < 8; ++g) {
            u32x4 xr[4], cr[2];
#pragma unroll
            for (int i = 0; i < 4; ++i)
                xr[i] = *(const u32x4*)&xs[tr * 4 + i][g * 4]; // broadcast across tc
            cr[0] = *(const u32x4*)&cs[tc][g * 4];
            cr[1] = *(const u32x4*)&cs[tc + 16][g * 4];
#pragma unroll
            for (int k2 = 0; k2 < 4; ++k2) {
#pragma unroll
                for (int i = 0; i < 4; ++i) {
                    h2 a = as_h2(xr[i][k2]);
#pragma unroll
                    for (int j = 0; j < 2; ++j) {
                        h2 d = a - as_h2(cr[j][k2]);           // v_pk_sub_f16
                        h2 ad = as_h2(as_u(d) & 0x7fff7fffu);  // abs both halves
                        acc[i][j] = __builtin_amdgcn_fdot2(ad, one2, acc[i][j], false);
                    }
                }
            }
        }
    }

    // epilogue: store sim + block max
    float m = 0.f;
#pragma unroll
    for (int i = 0; i < 4; ++i) {
        const int r = row0 + tr * 4 + i;
        S[r * DIM_O + col0 + tc]      = acc[i][0];
        S[r * DIM_O + col0 + tc + 16] = acc[i][1];
        m = fmaxf(m, fmaxf(acc[i][0], acc[i][1]));
    }
#pragma unroll
    for (int off = 32; off > 0; off >>= 1)
        m = fmaxf(m, __shfl_xor(m, off, 64));
    if (tid == 0) bmax[blockIdx.x] = m;
}

__global__ __launch_bounds__(256) void k_out(float* __restrict__ S,
                                             const float* __restrict__ beta,
                                             const float* __restrict__ bmax)
{
    const int tid = threadIdx.x;
    const int lane = tid & 63;
    float m = 0.f;
#pragma unroll
    for (int i = 0; i < 16; ++i) // 1024 block maxes
        m = fmaxf(m, bmax[lane + 64 * i]);
#pragma unroll
    for (int off = 32; off > 0; off >>= 1)
        m = fmaxf(m, __shfl_xor(m, off, 64));
    const float shift = m * W_DIST;

    const int f = blockIdx.x * 256 + tid; // float4 index, 131072 total
    f4 s = ((const f4*)S)[f];
    f4 b = ((const f4*)beta)[f & 127];
    f4 r;
    r.x = b.x * (shift - s.x);
    r.y = b.y * (shift - s.y);
    r.z = b.z * (shift - s.z);
    r.w = b.w * (shift - s.w);
    ((f4*)S)[f] = r;
}

extern "C" void kernel_launch(void* const* d_in, const int* in_sizes, int n_in,
                              void* d_out, int out_size, void* d_ws, size_t ws_size,
                              hipStream_t stream) {
    const float* X = (const float*)d_in[0];
    const float* C = (const float*)d_in[1];
    const float* beta = (const float*)d_in[2];
    float* S = (float*)d_out;     // sim staged in d_out, transformed in place
    float* bmax = (float*)d_ws;   // 1024 floats scratch
    k_sim<<<1024, 64, 0, stream>>>(X, C, S, bmax);
    k_out<<<512, 256, 0, stream>>>(S, beta, bmax);
}